// Round 5
// baseline (405.136 us; speedup 1.0000x reference)
//
#include <hip/hip_runtime.h>

#define IN_F 4096
#define OUT_F 4096
#define GS 128

// ---- GEMM geometry: 256x256 tile, BK=128 i8, 8 waves (2M x 4N), 512 thr ----
#define BM 256
#define BN 256
#define BKB 128                 // K-bytes (= i8 elements) per K-tile
#define NT (IN_F / BKB)         // 32 K-tiles
#define BUFB (BM * BKB)         // 32768 B per buffer per matrix

typedef int i32x4  __attribute__((ext_vector_type(4)));
typedef int i32x16 __attribute__((ext_vector_type(16)));

typedef __attribute__((address_space(1))) void void_g;
typedef __attribute__((address_space(3))) void void_l;

// Async global->LDS, 16B per lane. LDS dest = wave-uniform base + lane*16.
__device__ __forceinline__ void async_copy16(void* lds, const void* g) {
  __builtin_amdgcn_global_load_lds((const void_g*)g, (void_l*)lds, 16, 0, 0);
}

// Stage one block-wide 8KB chunk (64 rows x 128B) of `mat` K-tile k0 into LDS.
// LDS write is linear (lane d = tid*16); global source is pre-swizzled with the
// G4 3-bit XOR (byte ^= (row&7)<<4) so swizzled READS see logical data.
__device__ __forceinline__ void stage_g(signed char* region, int rowbase,
                                        const signed char* mat, int k0,
                                        int wave, int growl, int gcolb) {
  async_copy16(region + rowbase * BKB + wave * 1024,
               mat + (size_t)(rowbase + growl) * IN_F + k0 + gcolb);
}

// inv[perm[i]] = i
__global__ void invperm_kernel(const int* __restrict__ perm, int* __restrict__ inv) {
  int i = blockIdx.x * blockDim.x + threadIdx.x;
  inv[perm[i]] = i;
}

// Fused pre-processing: blocks [0,M) per-token int8 x-quant; blocks [M,M+OUT_F)
// dequant+perm+quant of W rows.
__global__ __launch_bounds__(256) void prep_kernel(
    const float* __restrict__ x,
    unsigned int* __restrict__ xq4,   // [M][IN_F/4]
    float* __restrict__ sx,           // [M]
    const int* __restrict__ wp,      // [OUT_F][IN_F/2]
    const float* __restrict__ wsc,   // [OUT_F][IN_F/GS]
    const int* __restrict__ inv,     // [IN_F]
    unsigned int* __restrict__ wq4,  // [OUT_F][IN_F/4]
    float* __restrict__ sw,          // [OUT_F]
    int M)
{
  __shared__ unsigned int prow[IN_F / 2];  // 8 KB (dequant path)
  __shared__ float srow[IN_F / GS];
  __shared__ float red[256];
  const int tid = threadIdx.x;
  const int b = blockIdx.x;

  if (b < M) {
    // ---- per-token x quantization ----
    const float4* x4 = (const float4*)(x + (size_t)b * IN_F);
    float4 v[4];
    float m = 0.f;
#pragma unroll
    for (int i = 0; i < 4; ++i) {
      v[i] = x4[tid + i * 256];
      m = fmaxf(m, fmaxf(fmaxf(fabsf(v[i].x), fabsf(v[i].y)),
                         fmaxf(fabsf(v[i].z), fabsf(v[i].w))));
    }
    red[tid] = m;
    __syncthreads();
#pragma unroll
    for (int s = 128; s > 0; s >>= 1) {
      if (tid < s) red[tid] = fmaxf(red[tid], red[tid + s]);
      __syncthreads();
    }
    const float mx = red[0];
    const float r = 127.0f / mx;
    if (tid == 0) sx[b] = mx * (1.0f / 127.0f);

    unsigned int* orow = xq4 + (size_t)b * (IN_F / 4);
#pragma unroll
    for (int i = 0; i < 4; ++i) {
      int q0 = (int)rintf(v[i].x * r);
      int q1 = (int)rintf(v[i].y * r);
      int q2 = (int)rintf(v[i].z * r);
      int q3 = (int)rintf(v[i].w * r);
      orow[tid + i * 256] = (unsigned)(q0 & 0xFF) | ((unsigned)(q1 & 0xFF) << 8) |
                            ((unsigned)(q2 & 0xFF) << 16) | ((unsigned)(q3 & 0xFF) << 24);
    }
  } else {
    // ---- W row: dequant + act-order permute + int8 re-quant ----
    const int o = b - M;
    const int4* wp4 = (const int4*)(wp + (size_t)o * (IN_F / 2));
    int4* p4 = (int4*)prow;
#pragma unroll
    for (int i = 0; i < 2; ++i)
      p4[tid + i * 256] = wp4[tid + i * 256];
    if (tid < IN_F / GS) srow[tid] = wsc[o * (IN_F / GS) + tid];
    __syncthreads();

    float m = 0.f;
#pragma unroll
    for (int c = 0; c < 8; ++c) {
      const int p = tid + c * 256;
      const unsigned bb = prow[p];
      const float s = srow[p >> 6];
      const float lo = (float)((int)(bb & 0xFu) - 8);
      const float hi = (float)((int)((bb >> 4) & 0xFu) - 8);
      m = fmaxf(m, fmaxf(fabsf(lo), fabsf(hi)) * s);
    }
    red[tid] = m;
    __syncthreads();
#pragma unroll
    for (int s = 128; s > 0; s >>= 1) {
      if (tid < s) red[tid] = fmaxf(red[tid], red[tid + s]);
      __syncthreads();
    }
    const float wmax = red[0];
    const float r = (wmax > 0.f) ? 127.0f / wmax : 0.f;
    if (tid == 0) sw[o] = wmax * (1.0f / 127.0f);

    unsigned int* orow = wq4 + (size_t)o * (IN_F / 4);
    const int4* inv4 = (const int4*)inv;
#pragma unroll
    for (int c = 0; c < 4; ++c) {
      const int p = tid + c * 256;
      const int4 iv = inv4[p];
      unsigned out = 0;
      const int idx[4] = {iv.x, iv.y, iv.z, iv.w};
#pragma unroll
      for (int e = 0; e < 4; ++e) {
        const int ii = idx[e];
        const unsigned wbits = prow[ii >> 1];
        const int n = (int)((wbits >> ((ii & 1) * 4)) & 0xFu) - 8;
        const float v = (float)n * srow[ii >> 7] * r;
        const int q = (int)rintf(v);
        out |= (unsigned)(q & 0xFF) << (e * 8);
      }
      orow[p] = out;
    }
  }
}

// ---- One K-tile, 4 phases, 1-phase-ahead A-frag register prefetch ----
// Phase p: {issue ds_reads for phase p+1; issue 2 stage_g; [pin]; lgkmcnt(4);
// MFMA m-block p (operands read LAST phase); [vmcnt(2) @p0/p2/p3]; barrier}.
// The prefetched reads complete DURING the MFMA burst -> LDS bandwidth
// overlaps the matrix pipe (the r3/r4 structures serialized them: 49% util).
//
// Read schedule (per wave): pre-loop issues mb0; p0 issues B(all 8)+mb1;
// p1 -> mb2; p2 -> mb3; p3 -> mb0 of t+1 (from nxt buffer).
// Uniform wait lgkmcnt(4) leaves only this phase's 4 A-prefetch reads in
// flight and drains everything older (incl. B at p0). sched_barrier(0) pins
// the B-group before the A-group at p0 so the counting is exact.
//
// Stage schedule (into nxt): p0: B[0:64),B[64:128); p1: A[0:64),A[128:192);
// p2: B[128:192),B[192:256); p3: A[64:128),A[192:256).
// vmcnt(2) at p0/p2/p3-end each drain the two OLDEST in-flight chunks:
//   carry-in {A64,A192}(cur) --p0-end--> drained (read @p1/p2: mb2,mb3)
//   {B0',B1',A0',A128'}     --p2-end--> drained (read @p3: mb0'; @p0': B')
//   {B2',B3'}               --p3-end--> drained (read @p0': B')
//   carry-out {A64',A192'}  -> next tile's p0-end.  Never vmcnt(0) mid-loop.
// Every drain is followed by s_barrier before any wave reads the chunk.
// Buffer overwrite safety: stages into nxt start @p0; all waves' last reads of
// that region (as cur of t-1) are >=4 barriers upstream.
// LAST tile: no stages; p0-end uses vmcnt(0) (drains the 2 old carried chunks);
// p3 issues no reads -> lgkmcnt(0).
template <bool LAST>
__device__ __forceinline__ void gemm_tile(
    const signed char* Ac, const signed char* Bc,
    signed char* An, signed char* Bn,
    const signed char* a_base, const signed char* b_base, int k0n,
    int wave, int aoff0, int boff0, const int (&kcs)[4],
    int growl, int gcolb, i32x4 (&aq)[2][4], i32x4 (&bq)[2][4],
    i32x16 (&acc)[4][2])
{
#pragma unroll
  for (int p = 0; p < 4; ++p) {
    // ---- ds_read issues (for phase p+1) ----
    if (p == 0) {
#pragma unroll
      for (int nb = 0; nb < 2; ++nb)
#pragma unroll
        for (int ks = 0; ks < 4; ++ks)
          bq[nb][ks] = *(const i32x4*)(Bc + boff0 + nb * 32 * BKB + kcs[ks]);
      __builtin_amdgcn_sched_barrier(0);   // pin B-group before A-group
#pragma unroll
      for (int ks = 0; ks < 4; ++ks)
        aq[0][ks] = *(const i32x4*)(Ac + aoff0 + 1 * 32 * BKB + kcs[ks]);
    } else if (p == 1) {
#pragma unroll
      for (int ks = 0; ks < 4; ++ks)
        aq[1][ks] = *(const i32x4*)(Ac + aoff0 + 2 * 32 * BKB + kcs[ks]);
    } else if (p == 2) {
#pragma unroll
      for (int ks = 0; ks < 4; ++ks)
        aq[0][ks] = *(const i32x4*)(Ac + aoff0 + 3 * 32 * BKB + kcs[ks]);
    } else if (!LAST) {
#pragma unroll
      for (int ks = 0; ks < 4; ++ks)
        aq[1][ks] = *(const i32x4*)(An + aoff0 + 0 * 32 * BKB + kcs[ks]);
    }
    // ---- staging issues (tile t+1) ----
    if (!LAST) {
      if (p == 0) {
        stage_g(Bn, 0, b_base, k0n, wave, growl, gcolb);
        stage_g(Bn, 64, b_base, k0n, wave, growl, gcolb);
      } else if (p == 1) {
        stage_g(An, 0, a_base, k0n, wave, growl, gcolb);
        stage_g(An, 128, a_base, k0n, wave, growl, gcolb);
      } else if (p == 2) {
        stage_g(Bn, 128, b_base, k0n, wave, growl, gcolb);
        stage_g(Bn, 192, b_base, k0n, wave, growl, gcolb);
      } else {
        stage_g(An, 64, a_base, k0n, wave, growl, gcolb);
        stage_g(An, 192, a_base, k0n, wave, growl, gcolb);
      }
    }
    // ---- wait for THIS phase's operands (issued last phase) ----
    if (p == 3 && LAST) { asm volatile("s_waitcnt lgkmcnt(0)" ::: "memory"); }
    else                { asm volatile("s_waitcnt lgkmcnt(4)" ::: "memory"); }
    __builtin_amdgcn_sched_barrier(0);   // rule #18: pin MFMA below the wait
    __builtin_amdgcn_s_setprio(1);
#pragma unroll
    for (int nb = 0; nb < 2; ++nb)
#pragma unroll
      for (int ks = 0; ks < 4; ++ks)
        acc[p][nb] = __builtin_amdgcn_mfma_i32_32x32x32_i8(
            aq[(p + 1) & 1][ks], bq[nb][ks], acc[p][nb], 0, 0, 0);
    __builtin_amdgcn_s_setprio(0);
    // ---- phase-end drains + barrier ----
    if (p == 0) {
      if (LAST) { asm volatile("s_waitcnt vmcnt(0)" ::: "memory"); }
      else      { asm volatile("s_waitcnt vmcnt(2)" ::: "memory"); }
      __builtin_amdgcn_sched_barrier(0);
    } else if ((p == 2 || p == 3) && !LAST) {
      asm volatile("s_waitcnt vmcnt(2)" ::: "memory");
      __builtin_amdgcn_sched_barrier(0);
    }
    __builtin_amdgcn_s_barrier();
  }
}

// C[M][N] = xq(i8) * wq(i8)^T scaled by sx[row]*sw[col] + bias.
// 256^2 tile, mfma_i32_32x32x32_i8 (4404 TOPS ceiling vs 3944 for 16x16x64),
// G4 3-bit XOR swizzle (conflict-free, verified r3: conflicts=0), counted
// vmcnt(2)/lgkmcnt(4) pipeline with 1-phase A-prefetch.
__global__ __launch_bounds__(512, 2) void gemm_kernel(
    const signed char* __restrict__ A,
    const signed char* __restrict__ B,
    const float* __restrict__ sx,
    const float* __restrict__ sw,
    const float* __restrict__ bias,
    float* __restrict__ C) {
  __shared__ __align__(16) signed char As[2 * BUFB];  // 64 KB
  __shared__ __align__(16) signed char Bs[2 * BUFB];  // 64 KB

  const int tid  = threadIdx.x;
  const int wave = tid >> 6;
  const int lane = tid & 63;
  const int l32  = lane & 31;
  const int lhi  = lane >> 5;

  const int bm = blockIdx.y;
  const int bn = blockIdx.x;
  const signed char* a_base = A + (size_t)bm * BM * IN_F;
  const signed char* b_base = B + (size_t)bn * BN * IN_F;

  // per-wave output strip: 128 rows x 64 cols (2M x 4N wave grid)
  const int wm = (wave >> 2) * 128;
  const int wn = (wave & 3) * 64;

  // read-side swizzle: fragment row = (strip base, mult of 32) + l32,
  // so row&7 == lane&7 for every fragment row.
  const int sxz = (lane & 7) << 4;
  // 32x32x32 i8 A/B frag: lane holds 16B at row = base + (lane&31),
  // byte col = ks*32 + (lane>>5)*16  (mirrors verified 16x16 pattern at 2x).
  int kcs[4];
#pragma unroll
  for (int ks = 0; ks < 4; ++ks) kcs[ks] = (ks * 32 + lhi * 16) ^ sxz;
  const int aoff0 = (wm + l32) * BKB;
  const int boff0 = (wn + l32) * BKB;

  // staging source pre-swizzle: lane writes LDS byte d = tid*16 within an 8KB
  // 64-row chunk; logical byte = d ^ ((row&7)<<4) with row = tid>>3.
  const int growl = tid >> 3;                                   // row 0..63
  const int gcolb = ((tid & 7) ^ ((tid >> 3) & 7)) << 4;        // 16B col

  i32x16 acc[4][2] = {};
  i32x4 aq[2][4];
  i32x4 bq[2][4];

  // Prologue: stage tile 0; order [B0,B1,B2,B3,A0,A128,A64,A192] so vmcnt(2)
  // drains all B + A0,A128 and leaves {A64,A192} as the steady-state carry.
  stage_g(Bs, 0, b_base, 0, wave, growl, gcolb);
  stage_g(Bs, 64, b_base, 0, wave, growl, gcolb);
  stage_g(Bs, 128, b_base, 0, wave, growl, gcolb);
  stage_g(Bs, 192, b_base, 0, wave, growl, gcolb);
  stage_g(As, 0, a_base, 0, wave, growl, gcolb);
  stage_g(As, 128, a_base, 0, wave, growl, gcolb);
  stage_g(As, 64, a_base, 0, wave, growl, gcolb);
  stage_g(As, 192, a_base, 0, wave, growl, gcolb);
  asm volatile("s_waitcnt vmcnt(2)" ::: "memory");
  __builtin_amdgcn_sched_barrier(0);
  __builtin_amdgcn_s_barrier();

  // Pre-issue mb0 reads (plays the role of "p3 of tile -1"); drained by the
  // uniform lgkmcnt(4) before tile 0's p0 MFMA.
#pragma unroll
  for (int ks = 0; ks < 4; ++ks)
    aq[1][ks] = *(const i32x4*)(As + aoff0 + kcs[ks]);

#pragma unroll 1
  for (int t = 0; t < NT - 1; ++t) {
    const int cur = t & 1;
    const int nxt = cur ^ 1;
    gemm_tile<false>(As + cur * BUFB, Bs + cur * BUFB,
                     As + nxt * BUFB, Bs + nxt * BUFB,
                     a_base, b_base, (t + 1) * BKB,
                     wave, aoff0, boff0, kcs, growl, gcolb, aq, bq, acc);
  }
  gemm_tile<true>(As + ((NT - 1) & 1) * BUFB, Bs + ((NT - 1) & 1) * BUFB,
                  nullptr, nullptr, a_base, b_base, 0,
                  wave, aoff0, boff0, kcs, growl, gcolb, aq, bq, acc);

  // Epilogue: stage scales+bias in LDS (final barrier of LAST tile guarantees
  // all waves' tile reads are complete before we overwrite As)
  float* sxs = (float*)As;          // 256 floats
  float* sws = sxs + BM;            // 256 floats
  float* bsh = sws + BN;            // 256 floats
  if (tid < BM) {
    sxs[tid] = sx[bm * BM + tid];
  } else {
    const int c = tid - BM;
    sws[c] = sw[bn * BN + c];
    bsh[c] = bias[bn * BN + c];
  }
  __syncthreads();

  // 32x32 C/D layout: col = lane&31, row = (reg&3) + 8*(reg>>2) + 4*(lane>>5)
  // (m74/m101, dtype-independent m121-m128). Nontemporal stores: C is not
  // re-read -> bypass L2 write-allocate (diagnostic for the 148MB FETCH).
  const int wm_g = bm * BM + wm;
  const int wn_g = bn * BN + wn;
#pragma unroll
  for (int nb = 0; nb < 2; ++nb) {
    const int col_l = wn + nb * 32 + l32;
    const float swv = sws[col_l];
    const float bv  = bsh[col_l];
    const int col = wn_g + nb * 32 + l32;
#pragma unroll
    for (int mb = 0; mb < 4; ++mb) {
#pragma unroll
      for (int r = 0; r < 16; ++r) {
        const int row_l = wm + mb * 32 + (r & 3) + 8 * (r >> 2) + 4 * lhi;
        const float val = (float)acc[mb][nb][r] * (sxs[row_l] * swv) + bv;
        __builtin_nontemporal_store(val, &C[(size_t)(wm_g - wm + row_l) * OUT_F + col]);
      }
    }
  }
}

extern "C" void kernel_launch(void* const* d_in, const int* in_sizes, int n_in,
                              void* d_out, int out_size, void* d_ws, size_t ws_size,
                              hipStream_t stream) {
  const float* x    = (const float*)d_in[0];
  const int*   wp   = (const int*)d_in[1];
  const float* wsc  = (const float*)d_in[2];
  const int*   perm = (const int*)d_in[3];
  const float* bias = (const float*)d_in[4];
  float* out = (float*)d_out;

  const int M = in_sizes[0] / IN_F;   // 8192 tokens

  // ws layout: xq [M][IN_F] i8 | wq [OUT_F][IN_F] i8 | sx [M] | sw [OUT_F] | inv [IN_F]
  signed char* xq = (signed char*)d_ws;
  signed char* wq = xq + (size_t)M * IN_F;
  float* sx = (float*)(wq + (size_t)OUT_F * IN_F);
  float* sw = sx + M;
  int* inv = (int*)(sw + OUT_F);

  invperm_kernel<<<IN_F / 256, 256, 0, stream>>>(perm, inv);

  prep_kernel<<<M + OUT_F, 256, 0, stream>>>(
      x, (unsigned int*)xq, sx, wp, wsc, inv, (unsigned int*)wq, sw, M);

  dim3 grid(OUT_F / BN, M / BM);   // (16, 32)
  gemm_kernel<<<grid, 512, 0, stream>>>(xq, wq, sx, sw, bias, out);
}

// Round 6
// 377.355 us; speedup vs baseline: 1.0736x; 1.0736x over previous
//
#include <hip/hip_runtime.h>

#define IN_F 4096
#define OUT_F 4096
#define GS 128

// ---- GEMM geometry: 256x256 tile, BK=128 i8, 8 waves (2M x 4N), 512 thr ----
#define BM 256
#define BN 256
#define BKB 128                 // K-bytes (= i8 elements) per K-tile
#define NT (IN_F / BKB)         // 32 K-tiles
#define BUFB (BM * BKB)         // 32768 B per buffer per matrix

typedef int i32x4 __attribute__((ext_vector_type(4)));

typedef __attribute__((address_space(1))) void void_g;
typedef __attribute__((address_space(3))) void void_l;

// Async global->LDS, 16B per lane. LDS dest = wave-uniform base + lane*16.
__device__ __forceinline__ void async_copy16(void* lds, const void* g) {
  __builtin_amdgcn_global_load_lds((const void_g*)g, (void_l*)lds, 16, 0, 0);
}

// Stage one block-wide 8KB chunk (64 rows x 128B) of `mat` K-tile k0 into LDS.
// LDS write is linear (lane d = tid*16); global source is pre-swizzled with the
// G4 3-bit XOR (byte ^= (row&7)<<4) so swizzled READS see logical data.
__device__ __forceinline__ void stage_g(signed char* region, int rowbase,
                                        const signed char* mat, int k0,
                                        int wave, int growl, int gcolb) {
  async_copy16(region + rowbase * BKB + wave * 1024,
               mat + (size_t)(rowbase + growl) * IN_F + k0 + gcolb);
}

// inv[perm[i]] = i
__global__ void invperm_kernel(const int* __restrict__ perm, int* __restrict__ inv) {
  int i = blockIdx.x * blockDim.x + threadIdx.x;
  inv[perm[i]] = i;
}

// Fused pre-processing: blocks [0,M) per-token int8 x-quant; blocks [M,M+OUT_F)
// dequant+perm+quant of W rows.
__global__ __launch_bounds__(256) void prep_kernel(
    const float* __restrict__ x,
    unsigned int* __restrict__ xq4,   // [M][IN_F/4]
    float* __restrict__ sx,           // [M]
    const int* __restrict__ wp,      // [OUT_F][IN_F/2]
    const float* __restrict__ wsc,   // [OUT_F][IN_F/GS]
    const int* __restrict__ inv,     // [IN_F]
    unsigned int* __restrict__ wq4,  // [OUT_F][IN_F/4]
    float* __restrict__ sw,          // [OUT_F]
    int M)
{
  __shared__ unsigned int prow[IN_F / 2];  // 8 KB (dequant path)
  __shared__ float srow[IN_F / GS];
  __shared__ float red[256];
  const int tid = threadIdx.x;
  const int b = blockIdx.x;

  if (b < M) {
    // ---- per-token x quantization ----
    const float4* x4 = (const float4*)(x + (size_t)b * IN_F);
    float4 v[4];
    float m = 0.f;
#pragma unroll
    for (int i = 0; i < 4; ++i) {
      v[i] = x4[tid + i * 256];
      m = fmaxf(m, fmaxf(fmaxf(fabsf(v[i].x), fabsf(v[i].y)),
                         fmaxf(fabsf(v[i].z), fabsf(v[i].w))));
    }
    red[tid] = m;
    __syncthreads();
#pragma unroll
    for (int s = 128; s > 0; s >>= 1) {
      if (tid < s) red[tid] = fmaxf(red[tid], red[tid + s]);
      __syncthreads();
    }
    const float mx = red[0];
    const float r = 127.0f / mx;
    if (tid == 0) sx[b] = mx * (1.0f / 127.0f);

    unsigned int* orow = xq4 + (size_t)b * (IN_F / 4);
#pragma unroll
    for (int i = 0; i < 4; ++i) {
      int q0 = (int)rintf(v[i].x * r);
      int q1 = (int)rintf(v[i].y * r);
      int q2 = (int)rintf(v[i].z * r);
      int q3 = (int)rintf(v[i].w * r);
      orow[tid + i * 256] = (unsigned)(q0 & 0xFF) | ((unsigned)(q1 & 0xFF) << 8) |
                            ((unsigned)(q2 & 0xFF) << 16) | ((unsigned)(q3 & 0xFF) << 24);
    }
  } else {
    // ---- W row: dequant + act-order permute + int8 re-quant ----
    const int o = b - M;
    const int4* wp4 = (const int4*)(wp + (size_t)o * (IN_F / 2));
    int4* p4 = (int4*)prow;
#pragma unroll
    for (int i = 0; i < 2; ++i)
      p4[tid + i * 256] = wp4[tid + i * 256];
    if (tid < IN_F / GS) srow[tid] = wsc[o * (IN_F / GS) + tid];
    __syncthreads();

    float m = 0.f;
#pragma unroll
    for (int c = 0; c < 8; ++c) {
      const int p = tid + c * 256;
      const unsigned bb = prow[p];
      const float s = srow[p >> 6];
      const float lo = (float)((int)(bb & 0xFu) - 8);
      const float hi = (float)((int)((bb >> 4) & 0xFu) - 8);
      m = fmaxf(m, fmaxf(fabsf(lo), fabsf(hi)) * s);
    }
    red[tid] = m;
    __syncthreads();
#pragma unroll
    for (int s = 128; s > 0; s >>= 1) {
      if (tid < s) red[tid] = fmaxf(red[tid], red[tid + s]);
      __syncthreads();
    }
    const float wmax = red[0];
    const float r = (wmax > 0.f) ? 127.0f / wmax : 0.f;
    if (tid == 0) sw[o] = wmax * (1.0f / 127.0f);

    unsigned int* orow = wq4 + (size_t)o * (IN_F / 4);
    const int4* inv4 = (const int4*)inv;
#pragma unroll
    for (int c = 0; c < 4; ++c) {
      const int p = tid + c * 256;
      const int4 iv = inv4[p];
      unsigned out = 0;
      const int idx[4] = {iv.x, iv.y, iv.z, iv.w};
#pragma unroll
      for (int e = 0; e < 4; ++e) {
        const int ii = idx[e];
        const unsigned wbits = prow[ii >> 1];
        const int n = (int)((wbits >> ((ii & 1) * 4)) & 0xFu) - 8;
        const float v = (float)n * srow[ii >> 7] * r;
        const int q = (int)rintf(v);
        out |= (unsigned)(q & 0xFF) << (e * 8);
      }
      orow[p] = out;
    }
  }
}

// ---- One K-tile, 4 phases, 1-phase-ahead A-frag register prefetch ----
// r3's verified 16x16x64 geometry + counted-lgkm overlap schedule.
// Phase p: {issue next phase's 4 A ds_reads (B: 8 reads at p0 only);
// issue 2 stage_g; lgkmcnt(4) [drains THIS phase's operands, leaves the
// prefetch in flight]; MFMA m-block p; [vmcnt(2) @p0/p2/p3-end + barrier]}.
// The prefetched reads complete DURING the MFMA burst -> LDS read bandwidth
// overlaps the matrix pipe (r3/r4 serialized them at ~42% MfmaUtil).
//
// lgkm FIFO accounting (DS queue is in-order; B-group pinned before A-group
// by sched_barrier so counts are exact). Per wave, steady state:
//   enter p0: 4 outstanding (mb0, prefetched at p3 of prev tile)
//   p0: +8 B +4 A(mb1) =16 -> lgkmcnt(4): drains mb0+B, leaves mb1
//   p1: +4 (mb2) =8 -> lgkmcnt(4): drains mb1 | p2: same for mb2/mb3
//   p3: +4 (mb0' from An) =8 -> lgkmcnt(4): drains mb3, carries mb0' out.
// LAST p3: no prefetch -> lgkmcnt(0).
//
// Stage schedule (into nxt): p0: B0',B1'; p1: A0',A128'; p2: B2',B3';
// p3: A64',A192'.  vmcnt(2) drains (oldest-first FIFO):
//   p0-end: carry{A64,A192}(cur)  [read @p1/p2: mb2,mb3 rows 64..127/192..255]
//   p2-end: {B0',B1',A0',A128'}   [A0'/A128' read @p3: mb0' prefetch]
//   p3-end: {B2',B3'}             [read @p0(t+1): B frags]
//   carry-out {A64',A192'}. Never vmcnt(0) mid-loop. Every drain is followed
//   by s_barrier before any wave reads the chunk (3 barriers/tile; p1-end has
//   no barrier - nothing new published, no overwrite hazard crossing it).
// Overwrite safety: stages into buffer `nxt` = cur(t-1); its last A-reads
// (mb3 @p2(t-1)) completed before p3(t-1)'s lgkmcnt, upstream of p3-end(t-1)
// barrier; its B-reads completed @p0(t-1). First overwrite @p0(t) is >=1
// barrier later.  LAST tile: no stages; p0-end uses vmcnt(0) (drains the 2
// carried chunks before mb2/mb3 reads); p3-end keeps the barrier (publishes
// before the epilogue overwrites As with scales).
template <bool LAST>
__device__ __forceinline__ void gemm_tile(
    const signed char* Ac, const signed char* Bc,
    signed char* An, signed char* Bn,
    const signed char* a_base, const signed char* b_base, int k0n,
    int wave, int wm, int wn, int l16, int quad, int sxz,
    int growl, int gcolb, i32x4 (&aq)[2][2][2], i32x4 (&bq)[4][2],
    i32x4 (&acc)[8][4])
{
#pragma unroll
  for (int p = 0; p < 4; ++p) {
    const int cb = p & 1;        // frag buffer for THIS phase (read last phase)
    const int nb = cb ^ 1;       // prefetch buffer
    if (p == 0) {
#pragma unroll
      for (int j = 0; j < 4; ++j)
#pragma unroll
        for (int ks = 0; ks < 2; ++ks)
          bq[j][ks] = *(const i32x4*)(Bc + (wn + j * 16 + l16) * BKB +
                                      ((ks * 64 + quad * 16) ^ sxz));
      __builtin_amdgcn_sched_barrier(0);   // B group strictly before A group
    }
    if (p < 3) {
#pragma unroll
      for (int i = 0; i < 2; ++i)
#pragma unroll
        for (int ks = 0; ks < 2; ++ks)
          aq[nb][i][ks] = *(const i32x4*)(Ac + (wm + (p + 1) * 32 + i * 16 + l16) * BKB +
                                          ((ks * 64 + quad * 16) ^ sxz));
    } else if (!LAST) {
#pragma unroll
      for (int i = 0; i < 2; ++i)
#pragma unroll
        for (int ks = 0; ks < 2; ++ks)
          aq[nb][i][ks] = *(const i32x4*)(An + (wm + i * 16 + l16) * BKB +
                                          ((ks * 64 + quad * 16) ^ sxz));
    }
    __builtin_amdgcn_sched_barrier(0);     // pin read issues above staging/wait
    if (!LAST) {
      if (p == 0) {
        stage_g(Bn, 0, b_base, k0n, wave, growl, gcolb);
        stage_g(Bn, 64, b_base, k0n, wave, growl, gcolb);
      } else if (p == 1) {
        stage_g(An, 0, a_base, k0n, wave, growl, gcolb);
        stage_g(An, 128, a_base, k0n, wave, growl, gcolb);
      } else if (p == 2) {
        stage_g(Bn, 128, b_base, k0n, wave, growl, gcolb);
        stage_g(Bn, 192, b_base, k0n, wave, growl, gcolb);
      } else {
        stage_g(An, 64, a_base, k0n, wave, growl, gcolb);
        stage_g(An, 192, a_base, k0n, wave, growl, gcolb);
      }
    }
    if (p == 3 && LAST) { asm volatile("s_waitcnt lgkmcnt(0)" ::: "memory"); }
    else                { asm volatile("s_waitcnt lgkmcnt(4)" ::: "memory"); }
    __builtin_amdgcn_sched_barrier(0);   // rule #18: pin MFMA below the wait
    __builtin_amdgcn_s_setprio(1);
#pragma unroll
    for (int i = 0; i < 2; ++i)
#pragma unroll
      for (int j = 0; j < 4; ++j)
#pragma unroll
        for (int ks = 0; ks < 2; ++ks)
          acc[2 * p + i][j] = __builtin_amdgcn_mfma_i32_16x16x64_i8(
              aq[cb][i][ks], bq[j][ks], acc[2 * p + i][j], 0, 0, 0);
    __builtin_amdgcn_s_setprio(0);
    if (p == 0) {
      if (LAST) { asm volatile("s_waitcnt vmcnt(0)" ::: "memory"); }
      else      { asm volatile("s_waitcnt vmcnt(2)" ::: "memory"); }
      __builtin_amdgcn_sched_barrier(0);
      __builtin_amdgcn_s_barrier();
    } else if (p == 2 && !LAST) {
      asm volatile("s_waitcnt vmcnt(2)" ::: "memory");
      __builtin_amdgcn_sched_barrier(0);
      __builtin_amdgcn_s_barrier();
    } else if (p == 3) {
      if (!LAST) { asm volatile("s_waitcnt vmcnt(2)" ::: "memory"); }
      __builtin_amdgcn_sched_barrier(0);
      __builtin_amdgcn_s_barrier();
    }
    // p1-end: no barrier
  }
}

// C[M][N] = xq(i8) * wq(i8)^T scaled by sx[row]*sw[col] + bias.
// 256^2 tile, mfma_i32_16x16x64_i8, G4 3-bit XOR swizzle (r3-verified
// conflict-free), counted vmcnt(2)/lgkmcnt(4) pipeline, 1-phase A-prefetch.
__global__ __launch_bounds__(512, 2) void gemm_kernel(
    const signed char* __restrict__ A,
    const signed char* __restrict__ B,
    const float* __restrict__ sx,
    const float* __restrict__ sw,
    const float* __restrict__ bias,
    float* __restrict__ C) {
  __shared__ __align__(16) signed char As[2 * BUFB];  // 64 KB
  __shared__ __align__(16) signed char Bs[2 * BUFB];  // 64 KB

  const int tid  = threadIdx.x;
  const int wave = tid >> 6;
  const int lane = tid & 63;
  const int quad = lane >> 4;
  const int l16  = lane & 15;

  const int bm = blockIdx.y;
  const int bn = blockIdx.x;
  const signed char* a_base = A + (size_t)bm * BM * IN_F;
  const signed char* b_base = B + (size_t)bn * BN * IN_F;

  // per-wave output strip: 128 rows x 64 cols (2M x 4N wave grid)
  const int wm = (wave >> 2) * 128;
  const int wn = (wave & 3) * 64;
  // read-side swizzle: row&7 == l16&7 for all fragment rows (strip offsets are
  // multiples of 16)
  const int sxz = (l16 & 7) << 4;

  // staging source pre-swizzle: lane writes LDS byte d = tid*16 within an 8KB
  // 64-row chunk; logical byte = d ^ ((row&7)<<4) with row = tid>>3.
  const int growl = tid >> 3;                                   // row 0..63
  const int gcolb = ((tid & 7) ^ ((tid >> 3) & 7)) << 4;        // 16B col

  i32x4 acc[8][4] = {};
  i32x4 aq[2][2][2];
  i32x4 bq[4][2];

  // Prologue: stage tile 0; order [B0,B1,B2,B3,A0,A128,A64,A192] so vmcnt(2)
  // drains all B + A0,A128 and leaves {A64,A192} as the steady-state carry.
  stage_g(Bs, 0, b_base, 0, wave, growl, gcolb);
  stage_g(Bs, 64, b_base, 0, wave, growl, gcolb);
  stage_g(Bs, 128, b_base, 0, wave, growl, gcolb);
  stage_g(Bs, 192, b_base, 0, wave, growl, gcolb);
  stage_g(As, 0, a_base, 0, wave, growl, gcolb);
  stage_g(As, 128, a_base, 0, wave, growl, gcolb);
  stage_g(As, 64, a_base, 0, wave, growl, gcolb);
  stage_g(As, 192, a_base, 0, wave, growl, gcolb);
  asm volatile("s_waitcnt vmcnt(2)" ::: "memory");
  __builtin_amdgcn_sched_barrier(0);
  __builtin_amdgcn_s_barrier();

  // Pre-issue mb0 reads for tile 0 (plays the role of "p3 of tile -1");
  // drained by the uniform lgkmcnt(4) at tile 0's p0 (A0 chunk is in LDS ^).
#pragma unroll
  for (int i = 0; i < 2; ++i)
#pragma unroll
    for (int ks = 0; ks < 2; ++ks)
      aq[0][i][ks] = *(const i32x4*)(As + (wm + i * 16 + l16) * BKB +
                                     ((ks * 64 + quad * 16) ^ sxz));

#pragma unroll 1
  for (int t = 0; t < NT - 1; ++t) {
    const int cur = t & 1;
    const int nxt = cur ^ 1;
    gemm_tile<false>(As + cur * BUFB, Bs + cur * BUFB,
                     As + nxt * BUFB, Bs + nxt * BUFB,
                     a_base, b_base, (t + 1) * BKB,
                     wave, wm, wn, l16, quad, sxz, growl, gcolb, aq, bq, acc);
  }
  gemm_tile<true>(As + ((NT - 1) & 1) * BUFB, Bs + ((NT - 1) & 1) * BUFB,
                  nullptr, nullptr, a_base, b_base, 0,
                  wave, wm, wn, l16, quad, sxz, growl, gcolb, aq, bq, acc);

  // Epilogue: stage scales+bias in LDS (p3-end barrier of LAST tile guarantees
  // all waves' tile reads are complete before we overwrite As)
  float* sxs = (float*)As;          // 256 floats
  float* sws = sxs + BM;            // 256 floats
  float* bsh = sws + BN;            // 256 floats
  if (tid < BM) {
    sxs[tid] = sx[bm * BM + tid];
  } else {
    const int c = tid - BM;
    sws[c] = sw[bn * BN + c];
    bsh[c] = bias[bn * BN + c];
  }
  __syncthreads();

  // C/D layout: col=lane&15, row=quad*4+reg (dtype-independent, m121-m128)
  const int wm_g = bm * BM + wm;
  const int wn_g = bn * BN + wn;
#pragma unroll
  for (int j = 0; j < 4; ++j) {
    const int col_l = wn + j * 16 + l16;
    const float swv = sws[col_l];
    const float bv  = bsh[col_l];
    const int col = wn_g + j * 16 + l16;
#pragma unroll
    for (int i = 0; i < 8; ++i) {
      const int row_l0 = wm + i * 16 + quad * 4;
      const int row0 = wm_g + i * 16 + quad * 4;
#pragma unroll
      for (int r = 0; r < 4; ++r)
        C[(size_t)(row0 + r) * OUT_F + col] =
            (float)acc[i][j][r] * (sxs[row_l0 + r] * swv) + bv;
    }
  }
}

extern "C" void kernel_launch(void* const* d_in, const int* in_sizes, int n_in,
                              void* d_out, int out_size, void* d_ws, size_t ws_size,
                              hipStream_t stream) {
  const float* x    = (const float*)d_in[0];
  const int*   wp   = (const int*)d_in[1];
  const float* wsc  = (const float*)d_in[2];
  const int*   perm = (const int*)d_in[3];
  const float* bias = (const float*)d_in[4];
  float* out = (float*)d_out;

  const int M = in_sizes[0] / IN_F;   // 8192 tokens

  // ws layout: xq [M][IN_F] i8 | wq [OUT_F][IN_F] i8 | sx [M] | sw [OUT_F] | inv [IN_F]
  signed char* xq = (signed char*)d_ws;
  signed char* wq = xq + (size_t)M * IN_F;
  float* sx = (float*)(wq + (size_t)OUT_F * IN_F);
  float* sw = sx + M;
  int* inv = (int*)(sw + OUT_F);

  invperm_kernel<<<IN_F / 256, 256, 0, stream>>>(perm, inv);

  prep_kernel<<<M + OUT_F, 256, 0, stream>>>(
      x, (unsigned int*)xq, sx, wp, wsc, inv, (unsigned int*)wq, sw, M);

  dim3 grid(OUT_F / BN, M / BM);   // (16, 32)
  gemm_kernel<<<grid, 512, 0, stream>>>(xq, wq, sx, sw, bias, out);
}

// Round 7
// 368.222 us; speedup vs baseline: 1.1003x; 1.0248x over previous
//
#include <hip/hip_runtime.h>

#define IN_F 4096
#define OUT_F 4096
#define GS 128

// ---- GEMM geometry: 256x256 tile, BK=128 i8, 8 waves (2M x 4N), 512 thr ----
#define BM 256
#define BN 256
#define BKB 128                 // K-bytes (= i8 elements) per K-tile
#define NT (IN_F / BKB)         // 32 K-tiles
#define BUFB (BM * BKB)         // 32768 B per buffer per matrix

typedef int i32x4 __attribute__((ext_vector_type(4)));

typedef __attribute__((address_space(1))) void void_g;
typedef __attribute__((address_space(3))) void void_l;

// Async global->LDS, 16B per lane. LDS dest = wave-uniform base + lane*16.
__device__ __forceinline__ void async_copy16(void* lds, const void* g) {
  __builtin_amdgcn_global_load_lds((const void_g*)g, (void_l*)lds, 16, 0, 0);
}

// Stage one block-wide 8KB chunk (64 rows x 128B) of `mat` K-tile k0 into LDS.
// LDS write is linear (lane d = tid*16); global source is pre-swizzled with the
// G4 3-bit XOR (byte ^= (row&7)<<4) so swizzled READS see logical data.
__device__ __forceinline__ void stage_g(signed char* region, int rowbase,
                                        const signed char* mat, int k0,
                                        int wave, int growl, int gcolb) {
  async_copy16(region + rowbase * BKB + wave * 1024,
               mat + (size_t)(rowbase + growl) * IN_F + k0 + gcolb);
}

// Fused pre-processing, 2 paths:
//  blocks [0,M):        per-token x-quant IN PERMUTED ORDER:
//                       xq[t][k] = q(x[t][perm[k]])  (gather via LDS row copy).
//  blocks [M,M+OUT_F):  W dequant + int8 re-quant in NATURAL order (linear).
// y = sum_k xq[t][k]*wq[o][k] = sum_k x[t,perm[k]]*W[o,k] == reference.
// This removes the inverse-perm kernel and the W-side random gather.
__global__ __launch_bounds__(256) void prep_kernel(
    const float* __restrict__ x,
    unsigned int* __restrict__ xq4,   // [M][IN_F/4]
    float* __restrict__ sx,           // [M]
    const int* __restrict__ wp,      // [OUT_F][IN_F/2]
    const float* __restrict__ wsc,   // [OUT_F][IN_F/GS]
    const int* __restrict__ perm,    // [IN_F]
    unsigned int* __restrict__ wq4,  // [OUT_F][IN_F/4]
    float* __restrict__ sw,          // [OUT_F]
    int M)
{
  __shared__ float xrow[IN_F];             // 16 KB (x path)
  __shared__ unsigned int prow[IN_F / 2];  // 8 KB (w path)
  __shared__ float srow[IN_F / GS];
  __shared__ float red[256];
  const int tid = threadIdx.x;
  const int b = blockIdx.x;

  if (b < M) {
    // ---- per-token x quantization, permuted output order ----
    const float4* x4 = (const float4*)(x + (size_t)b * IN_F);
    float4* xr4 = (float4*)xrow;
    float m = 0.f;
#pragma unroll
    for (int i = 0; i < 4; ++i) {
      float4 v = x4[tid + i * 256];
      xr4[tid + i * 256] = v;   // stage row for the gather (absmax is perm-inv)
      m = fmaxf(m, fmaxf(fmaxf(fabsf(v.x), fabsf(v.y)),
                         fmaxf(fabsf(v.z), fabsf(v.w))));
    }
    red[tid] = m;
    __syncthreads();            // also publishes xrow
#pragma unroll
    for (int s = 128; s > 0; s >>= 1) {
      if (tid < s) red[tid] = fmaxf(red[tid], red[tid + s]);
      __syncthreads();
    }
    const float mx = red[0];
    const float r = 127.0f / mx;
    if (tid == 0) sx[b] = mx * (1.0f / 127.0f);

    unsigned int* orow = xq4 + (size_t)b * (IN_F / 4);
    const int4* perm4 = (const int4*)perm;
#pragma unroll
    for (int c = 0; c < 4; ++c) {
      const int p = tid + c * 256;
      const int4 pv = perm4[p];            // coalesced 16B
      int q0 = (int)rintf(xrow[pv.x] * r);
      int q1 = (int)rintf(xrow[pv.y] * r);
      int q2 = (int)rintf(xrow[pv.z] * r);
      int q3 = (int)rintf(xrow[pv.w] * r);
      orow[p] = (unsigned)(q0 & 0xFF) | ((unsigned)(q1 & 0xFF) << 8) |
                ((unsigned)(q2 & 0xFF) << 16) | ((unsigned)(q3 & 0xFF) << 24);
    }
  } else {
    // ---- W row: dequant + int8 re-quant, natural order (linear unpack) ----
    const int o = b - M;
    const int4* wp4 = (const int4*)(wp + (size_t)o * (IN_F / 2));
    int4* p4 = (int4*)prow;
#pragma unroll
    for (int i = 0; i < 2; ++i)
      p4[tid + i * 256] = wp4[tid + i * 256];
    if (tid < IN_F / GS) srow[tid] = wsc[o * (IN_F / GS) + tid];
    __syncthreads();

    float m = 0.f;
#pragma unroll
    for (int c = 0; c < 8; ++c) {
      const int p = tid + c * 256;
      const unsigned bb = prow[p];
      const float s = srow[p >> 6];
      const float lo = (float)((int)(bb & 0xFu) - 8);
      const float hi = (float)((int)((bb >> 4) & 0xFu) - 8);
      m = fmaxf(m, fmaxf(fabsf(lo), fabsf(hi)) * s);
    }
    red[tid] = m;
    __syncthreads();
#pragma unroll
    for (int s = 128; s > 0; s >>= 1) {
      if (tid < s) red[tid] = fmaxf(red[tid], red[tid + s]);
      __syncthreads();
    }
    const float wmax = red[0];
    const float r = (wmax > 0.f) ? 127.0f / wmax : 0.f;
    if (tid == 0) sw[o] = wmax * (1.0f / 127.0f);

    // output word p covers k = 4p..4p+3: bytes prow[2p] (k=4p,4p+1) and
    // prow[2p+1] (k=4p+2,4p+3); scale group = 4p/GS = p>>5 (uniform per word).
    unsigned int* orow = wq4 + (size_t)o * (IN_F / 4);
#pragma unroll
    for (int c = 0; c < 4; ++c) {
      const int p = tid + c * 256;
      const unsigned b0 = prow[2 * p];
      const unsigned b1 = prow[2 * p + 1];
      const float s = srow[p >> 5] * r;
      int q0 = (int)rintf((float)((int)(b0 & 0xFu) - 8) * s);
      int q1 = (int)rintf((float)((int)((b0 >> 4) & 0xFu) - 8) * s);
      int q2 = (int)rintf((float)((int)(b1 & 0xFu) - 8) * s);
      int q3 = (int)rintf((float)((int)((b1 >> 4) & 0xFu) - 8) * s);
      orow[p] = (unsigned)(q0 & 0xFF) | ((unsigned)(q1 & 0xFF) << 8) |
                ((unsigned)(q2 & 0xFF) << 16) | ((unsigned)(q3 & 0xFF) << 24);
    }
  }
}

// ---- One K-tile, 4 phases, 1-phase-ahead A-frag register prefetch ----
// r6 schedule (verified: conflicts=0, best gemm so far) with CUR as a template
// parameter (t-loop unrolled x2) so every ds_read decomposes to
// {per-thread base VGPR} + {compile-time immediate offset}. r6's PMC showed
// VALUBusy ~20% = per-tile address recomputation forced by the 256-unified-reg
// boundary (VGPR 128 + acc 128 AGPR); immediate-offset addressing needs only
// ~4 base regs per matrix and no per-tile VALU.
//
// lgkm FIFO accounting (per wave, steady state) — identical to r6:
//   enter p0: 4 outstanding (mb0, prefetched at p3 of prev tile)
//   p0: +8 B +4 A(mb1) =16 -> lgkmcnt(4): drains mb0+B, leaves mb1
//   p1: +4 (mb2) =8 -> lgkmcnt(4) | p2: +4 (mb3) =8 -> lgkmcnt(4)
//   p3: +4 (mb0' from nxt) =8 -> lgkmcnt(4): drains mb3, carries mb0'.
//   LAST p3: no prefetch -> lgkmcnt(0).
// Stage schedule (into nxt): p0: B0',B1'; p1: A0',A128'; p2: B2',B3';
// p3: A64',A192'.  vmcnt(2) drains (oldest-first):
//   p0-end: carry{A64,A192}(cur) [read @p1/p2: mb2,mb3]
//   p2-end: {B0',B1',A0',A128'} [A0'/A128' read @p3 prefetch]
//   p3-end: {B2',B3'} [read @p0(t+1)] ; carry {A64',A192'}.
// Never vmcnt(0) mid-loop; every drain is followed by s_barrier before any
// wave reads the chunk. Overwrite safety: first store into nxt (@p0) is >=1
// barrier after all waves' last reads of that buffer (as cur of t-1).
// LAST: p0-end vmcnt(0); p3-end barrier kept (epilogue reuses As).
template <int CUR, bool LAST>
__device__ __forceinline__ void gemm_tile(
    signed char* As, signed char* Bs,
    const signed char* a_base, const signed char* b_base, int k0n,
    int wave, int a_row, int b_row, const int (&lp)[2],
    int growl, int gcolb, i32x4 (&aq)[2][2][2], i32x4 (&bq)[4][2],
    i32x4 (&acc)[8][4])
{
  const signed char* a_l  = As + CUR * BUFB + a_row;        // (wm+l16)*BKB
  const signed char* b_l  = Bs + CUR * BUFB + b_row;
  const signed char* an_l = As + (CUR ^ 1) * BUFB + a_row;
  signed char* Anw = As + (CUR ^ 1) * BUFB;
  signed char* Bnw = Bs + (CUR ^ 1) * BUFB;
#pragma unroll
  for (int p = 0; p < 4; ++p) {
    const int cb = p & 1;        // frag buffer for THIS phase (read last phase)
    const int nb = cb ^ 1;       // prefetch buffer
    if (p == 0) {
#pragma unroll
      for (int j = 0; j < 4; ++j)
#pragma unroll
        for (int ks = 0; ks < 2; ++ks)
          bq[j][ks] = *(const i32x4*)(b_l + j * 16 * BKB + lp[ks]);
      __builtin_amdgcn_sched_barrier(0);   // B group strictly before A group
    }
    if (p < 3) {
#pragma unroll
      for (int i = 0; i < 2; ++i)
#pragma unroll
        for (int ks = 0; ks < 2; ++ks)
          aq[nb][i][ks] = *(const i32x4*)(a_l + ((p + 1) * 32 + i * 16) * BKB + lp[ks]);
    } else if (!LAST) {
#pragma unroll
      for (int i = 0; i < 2; ++i)
#pragma unroll
        for (int ks = 0; ks < 2; ++ks)
          aq[nb][i][ks] = *(const i32x4*)(an_l + i * 16 * BKB + lp[ks]);
    }
    __builtin_amdgcn_sched_barrier(0);     // pin read issues above staging/wait
    if (!LAST) {
      if (p == 0) {
        stage_g(Bnw, 0, b_base, k0n, wave, growl, gcolb);
        stage_g(Bnw, 64, b_base, k0n, wave, growl, gcolb);
      } else if (p == 1) {
        stage_g(Anw, 0, a_base, k0n, wave, growl, gcolb);
        stage_g(Anw, 128, a_base, k0n, wave, growl, gcolb);
      } else if (p == 2) {
        stage_g(Bnw, 128, b_base, k0n, wave, growl, gcolb);
        stage_g(Bnw, 192, b_base, k0n, wave, growl, gcolb);
      } else {
        stage_g(Anw, 64, a_base, k0n, wave, growl, gcolb);
        stage_g(Anw, 192, a_base, k0n, wave, growl, gcolb);
      }
    }
    if (p == 3 && LAST) { asm volatile("s_waitcnt lgkmcnt(0)" ::: "memory"); }
    else                { asm volatile("s_waitcnt lgkmcnt(4)" ::: "memory"); }
    __builtin_amdgcn_sched_barrier(0);   // rule #18: pin MFMA below the wait
    __builtin_amdgcn_s_setprio(1);
#pragma unroll
    for (int i = 0; i < 2; ++i)
#pragma unroll
      for (int j = 0; j < 4; ++j)
#pragma unroll
        for (int ks = 0; ks < 2; ++ks)
          acc[2 * p + i][j] = __builtin_amdgcn_mfma_i32_16x16x64_i8(
              aq[cb][i][ks], bq[j][ks], acc[2 * p + i][j], 0, 0, 0);
    __builtin_amdgcn_s_setprio(0);
    if (p == 0) {
      if (LAST) { asm volatile("s_waitcnt vmcnt(0)" ::: "memory"); }
      else      { asm volatile("s_waitcnt vmcnt(2)" ::: "memory"); }
      __builtin_amdgcn_sched_barrier(0);
      __builtin_amdgcn_s_barrier();
    } else if (p == 2 && !LAST) {
      asm volatile("s_waitcnt vmcnt(2)" ::: "memory");
      __builtin_amdgcn_sched_barrier(0);
      __builtin_amdgcn_s_barrier();
    } else if (p == 3) {
      if (!LAST) { asm volatile("s_waitcnt vmcnt(2)" ::: "memory"); }
      __builtin_amdgcn_sched_barrier(0);
      __builtin_amdgcn_s_barrier();
    }
    // p1-end: no barrier
  }
}

// C[M][N] = xq(i8, perm'd) * wq(i8, natural)^T scaled by sx[row]*sw[col]+bias.
__global__ __launch_bounds__(512, 2) void gemm_kernel(
    const signed char* __restrict__ A,
    const signed char* __restrict__ B,
    const float* __restrict__ sx,
    const float* __restrict__ sw,
    const float* __restrict__ bias,
    float* __restrict__ C) {
  __shared__ __align__(16) signed char As[2 * BUFB];  // 64 KB
  __shared__ __align__(16) signed char Bs[2 * BUFB];  // 64 KB

  const int tid  = threadIdx.x;
  const int wave = tid >> 6;
  const int lane = tid & 63;
  const int quad = lane >> 4;
  const int l16  = lane & 15;

  const int bm = blockIdx.y;
  const int bn = blockIdx.x;
  const signed char* a_base = A + (size_t)bm * BM * IN_F;
  const signed char* b_base = B + (size_t)bn * BN * IN_F;

  // per-wave output strip: 128 rows x 64 cols (2M x 4N wave grid)
  const int wm = (wave >> 2) * 128;
  const int wn = (wave & 3) * 64;
  // read-side swizzle: row&7 == l16&7 (strip offsets are multiples of 16)
  const int sxz = (l16 & 7) << 4;
  // lane-dependent byte offset within a row, per ks half (the ONLY per-lane
  // part of every fragment address; the rest is compile-time immediate)
  int lp[2];
#pragma unroll
  for (int ks = 0; ks < 2; ++ks) lp[ks] = (ks * 64 + quad * 16) ^ sxz;
  const int a_row = (wm + l16) * BKB;
  const int b_row = (wn + l16) * BKB;

  // staging source pre-swizzle: lane writes LDS byte d = tid*16 within an 8KB
  // 64-row chunk; logical byte = d ^ ((row&7)<<4) with row = tid>>3.
  const int growl = tid >> 3;                                   // row 0..63
  const int gcolb = ((tid & 7) ^ ((tid >> 3) & 7)) << 4;        // 16B col

  i32x4 acc[8][4] = {};
  i32x4 aq[2][2][2];
  i32x4 bq[4][2];

  // Prologue: stage tile 0; order [B0,B1,B2,B3,A0,A128,A64,A192] so vmcnt(2)
  // drains all B + A0,A128 and leaves {A64,A192} as the steady-state carry.
  stage_g(Bs, 0, b_base, 0, wave, growl, gcolb);
  stage_g(Bs, 64, b_base, 0, wave, growl, gcolb);
  stage_g(Bs, 128, b_base, 0, wave, growl, gcolb);
  stage_g(Bs, 192, b_base, 0, wave, growl, gcolb);
  stage_g(As, 0, a_base, 0, wave, growl, gcolb);
  stage_g(As, 128, a_base, 0, wave, growl, gcolb);
  stage_g(As, 64, a_base, 0, wave, growl, gcolb);
  stage_g(As, 192, a_base, 0, wave, growl, gcolb);
  asm volatile("s_waitcnt vmcnt(2)" ::: "memory");
  __builtin_amdgcn_sched_barrier(0);
  __builtin_amdgcn_s_barrier();

  // Pre-issue mb0 reads for tile 0 ("p3 of tile -1"); drained by the uniform
  // lgkmcnt(4) at tile 0's p0.
#pragma unroll
  for (int i = 0; i < 2; ++i)
#pragma unroll
    for (int ks = 0; ks < 2; ++ks)
      aq[0][i][ks] = *(const i32x4*)(As + a_row + i * 16 * BKB + lp[ks]);

  // NT-1 = 31 non-last tiles: 15 unrolled pairs + one, then LAST from buf 1.
#pragma unroll 1
  for (int t = 0; t + 2 <= NT - 1; t += 2) {
    gemm_tile<0, false>(As, Bs, a_base, b_base, (t + 1) * BKB,
                        wave, a_row, b_row, lp, growl, gcolb, aq, bq, acc);
    gemm_tile<1, false>(As, Bs, a_base, b_base, (t + 2) * BKB,
                        wave, a_row, b_row, lp, growl, gcolb, aq, bq, acc);
  }
  gemm_tile<0, false>(As, Bs, a_base, b_base, (NT - 1) * BKB,
                      wave, a_row, b_row, lp, growl, gcolb, aq, bq, acc);
  gemm_tile<1, true>(As, Bs, a_base, b_base, 0,
                     wave, a_row, b_row, lp, growl, gcolb, aq, bq, acc);

  // Epilogue: stage scales+bias in LDS (p3-end barrier of LAST tile guarantees
  // all waves' tile reads are complete before we overwrite As)
  float* sxs = (float*)As;          // 256 floats
  float* sws = sxs + BM;            // 256 floats
  float* bsh = sws + BN;            // 256 floats
  if (tid < BM) {
    sxs[tid] = sx[bm * BM + tid];
  } else {
    const int c = tid - BM;
    sws[c] = sw[bn * BN + c];
    bsh[c] = bias[bn * BN + c];
  }
  __syncthreads();

  // C/D layout: col=lane&15, row=quad*4+reg (dtype-independent, m121-m128)
  const int wm_g = bm * BM + wm;
  const int wn_g = bn * BN + wn;
#pragma unroll
  for (int j = 0; j < 4; ++j) {
    const int col_l = wn + j * 16 + l16;
    const float swv = sws[col_l];
    const float bv  = bsh[col_l];
    const int col = wn_g + j * 16 + l16;
#pragma unroll
    for (int i = 0; i < 8; ++i) {
      const int row_l0 = wm + i * 16 + quad * 4;
      const int row0 = wm_g + i * 16 + quad * 4;
#pragma unroll
      for (int r = 0; r < 4; ++r)
        C[(size_t)(row0 + r) * OUT_F + col] =
            (float)acc[i][j][r] * (sxs[row_l0 + r] * swv) + bv;
    }
  }
}

extern "C" void kernel_launch(void* const* d_in, const int* in_sizes, int n_in,
                              void* d_out, int out_size, void* d_ws, size_t ws_size,
                              hipStream_t stream) {
  const float* x    = (const float*)d_in[0];
  const int*   wp   = (const int*)d_in[1];
  const float* wsc  = (const float*)d_in[2];
  const int*   perm = (const int*)d_in[3];
  const float* bias = (const float*)d_in[4];
  float* out = (float*)d_out;

  const int M = in_sizes[0] / IN_F;   // 8192 tokens

  // ws layout: xq [M][IN_F] i8 | wq [OUT_F][IN_F] i8 | sx [M] | sw [OUT_F]
  signed char* xq = (signed char*)d_ws;
  signed char* wq = xq + (size_t)M * IN_F;
  float* sx = (float*)(wq + (size_t)OUT_F * IN_F);
  float* sw = sx + M;

  prep_kernel<<<M + OUT_F, 256, 0, stream>>>(
      x, (unsigned int*)xq, sx, wp, wsc, perm, (unsigned int*)wq, sw, M);

  dim3 grid(OUT_F / BN, M / BM);   // (16, 32)
  gemm_kernel<<<grid, 512, 0, stream>>>(xq, wq, sx, sw, bias, out);
}